// Round 1
// baseline (1845.116 us; speedup 1.0000x reference)
//
#include <hip/hip_runtime.h>

#define BATCH 16
#define QT    2048
#define KTOT  2048
#define DIM   1024

typedef __attribute__((ext_vector_type(8))) short          s16x8;  // bf16 MFMA frag
typedef __attribute__((ext_vector_type(4))) float          f32x4;
typedef __attribute__((ext_vector_type(4))) unsigned short us4;
typedef __attribute__((ext_vector_type(8))) unsigned short us8;
typedef unsigned short u16;

__device__ __forceinline__ u16 f2bf(float x) {
    unsigned u = __builtin_bit_cast(unsigned, x);
    u = u + 0x7fffu + ((u >> 16) & 1u);          // RNE
    return (u16)(u >> 16);
}
__device__ __forceinline__ float bf2f(u16 h) {
    unsigned u = ((unsigned)h) << 16;
    return __builtin_bit_cast(float, u);
}

// ---------------------------------------------------------------------------
// Rows with q >= Q_len: reference softmax is exactly uniform 1/KTOT over ALL
// k (valid and invalid) -> output = column mean of V. Also covers the poison
// re-init of d_out for those rows.
__global__ __launch_bounds__(256) void fill_mean(const float* __restrict__ V,
                                                 const int* __restrict__ Qlen,
                                                 float* __restrict__ out) {
    const int b  = blockIdx.x >> 4;
    const int d0 = (blockIdx.x & 15) << 6;
    const int qlen = Qlen[b];
    const int tid = threadIdx.x;
    const int dc = d0 + (tid & 63);
    const int part = tid >> 6;
    __shared__ float red[4][64];
    __shared__ float mcol[64];
    float sm = 0.0f;
    for (int kt = part; kt < KTOT; kt += 4)
        sm += V[((size_t)(b * KTOT + kt)) * DIM + dc];
    red[part][tid & 63] = sm;
    __syncthreads();
    if (tid < 64)
        mcol[tid] = (red[0][tid] + red[1][tid] + red[2][tid] + red[3][tid]) * (1.0f / (float)KTOT);
    __syncthreads();
    const float mv = mcol[tid & 63];
    for (int q = qlen + part; q < QT; q += 4)
        out[((size_t)(b * QT + q)) * DIM + dc] = mv;
}

// ---------------------------------------------------------------------------
// K -> (hi, lo) bf16 split, elementwise. 8 elements / thread.
__global__ __launch_bounds__(256) void conv_k(const float* __restrict__ K,
                                              u16* __restrict__ hi, u16* __restrict__ lo) {
    const size_t idx = ((size_t)blockIdx.x * 256 + threadIdx.x) * 8;
    f32x4 a0 = *(const f32x4*)(K + idx);
    f32x4 a1 = *(const f32x4*)(K + idx + 4);
    us8 h, l;
#pragma unroll
    for (int j = 0; j < 4; ++j) {
        u16 h0 = f2bf(a0[j]); h[j]     = h0; l[j]     = f2bf(a0[j] - bf2f(h0));
        u16 h1 = f2bf(a1[j]); h[4 + j] = h1; l[4 + j] = f2bf(a1[j] - bf2f(h1));
    }
    *(us8*)(hi + idx) = h;
    *(us8*)(lo + idx) = l;
}

// ---------------------------------------------------------------------------
// V[b][kt][d] fp32 -> Vt[b][d][kt] bf16 (so PV B-fragments are 16B-contiguous)
__global__ __launch_bounds__(256) void trans_v(const float* __restrict__ V,
                                               u16* __restrict__ Vt) {
    const int blk = blockIdx.x;
    const int b   = blk >> 9;
    const int kt0 = ((blk >> 4) & 31) << 6;
    const int d0  = (blk & 15) << 6;
    __shared__ u16 tbuf[64][65];
    const int tid = threadIdx.x;
    const int cr  = tid >> 4;
    const int c4  = (tid & 15) << 2;
#pragma unroll
    for (int p = 0; p < 4; ++p) {
        const int r = cr + p * 16;
        f32x4 v = *(const f32x4*)(V + ((size_t)(b * KTOT + kt0 + r)) * DIM + d0 + c4);
#pragma unroll
        for (int j = 0; j < 4; ++j) tbuf[r][c4 + j] = f2bf(v[j]);
    }
    __syncthreads();
#pragma unroll
    for (int p = 0; p < 4; ++p) {
        const int dr = cr + p * 16;
        us4 o;
#pragma unroll
        for (int j = 0; j < 4; ++j) o[j] = tbuf[c4 + j][dr];
        *(us4*)(Vt + ((size_t)(b * DIM + d0 + dr)) * KTOT + kt0 + c4) = o;
    }
}

// ---------------------------------------------------------------------------
// Main flash kernel. Block = 256 thr = 4 waves. M=32 q rows / block.
// Wave w owns D-slice [256w, 256w+256): computes partial S over its slice
// (reduced in LDS) and the O columns of its slice.
// QK^T in split-bf16 (3 MFMA terms) for fp32-grade logits.
__global__ __launch_bounds__(256, 1) void attn_main(
    const float* __restrict__ Q, const int* __restrict__ Qlen, const int* __restrict__ Klen,
    const u16* __restrict__ Khi, const u16* __restrict__ Klo, const u16* __restrict__ Vt,
    float* __restrict__ out) {
    const int blk  = blockIdx.x;
    const int b    = blk >> 6;
    const int qt   = (blk & 63) << 5;
    const int qlen = Qlen[b];
    if (qt >= qlen) return;                    // fill_mean covers these rows
    const int klen = Klen[b];
    const int nkt  = (klen + 31) >> 5;

    const int tid  = threadIdx.x;
    const int w    = tid >> 6;
    const int ln   = tid & 63;
    const int l16  = ln & 15;
    const int quad = ln >> 4;

    __shared__ float sred[4][32][33];          // partial S, stride 33 (2-way max)
    __shared__ float rowred[32][8];
    __shared__ float mrow[32], lrow[32], arow[32];
    __shared__ u16   pbuf[32][36];             // P bf16, stride 36 (8B-aligned rows)

    if (tid < 32) { mrow[tid] = -3.0e38f; lrow[tid] = 0.0f; }

    // --- Q fragments (A-layout), split hi/lo, resident in registers ---------
    s16x8 qhi[2][8], qlo[2][8];
#pragma unroll
    for (int mi = 0; mi < 2; ++mi)
#pragma unroll
        for (int kc = 0; kc < 8; ++kc) {
            const float* src = Q + ((size_t)(b * QT + qt + mi * 16 + l16)) * DIM
                                 + w * 256 + kc * 32 + quad * 8;
            f32x4 a0 = *(const f32x4*)src;
            f32x4 a1 = *(const f32x4*)(src + 4);
            s16x8 h, l;
#pragma unroll
            for (int j = 0; j < 4; ++j) {
                u16 h0 = f2bf(a0[j]); h[j]     = (short)h0; l[j]     = (short)f2bf(a0[j] - bf2f(h0));
                u16 h1 = f2bf(a1[j]); h[4 + j] = (short)h1; l[4 + j] = (short)f2bf(a1[j] - bf2f(h1));
            }
            qhi[mi][kc] = h; qlo[mi][kc] = l;
        }

    f32x4 o[2][16];
    const f32x4 fzero = {0.0f, 0.0f, 0.0f, 0.0f};
#pragma unroll
    for (int mi = 0; mi < 2; ++mi)
#pragma unroll
        for (int nd = 0; nd < 16; ++nd) o[mi][nd] = fzero;

    __syncthreads();

    for (int t = 0; t < nkt; ++t) {
        const int kt0 = t << 5;
        // --- QK^T partial over this wave's D-slice (3-term split bf16) -----
        f32x4 s[2][2];
        s[0][0] = fzero; s[0][1] = fzero; s[1][0] = fzero; s[1][1] = fzero;
#pragma unroll
        for (int ni = 0; ni < 2; ++ni) {
            const size_t koff = ((size_t)(b * KTOT + kt0 + ni * 16 + l16)) * DIM
                              + w * 256 + quad * 8;
            const u16* kh = Khi + koff;
            const u16* kl = Klo + koff;
#pragma unroll
            for (int kc = 0; kc < 8; ++kc) {
                s16x8 bh = *(const s16x8*)(kh + kc * 32);
                s16x8 bl = *(const s16x8*)(kl + kc * 32);
                s[0][ni] = __builtin_amdgcn_mfma_f32_16x16x32_bf16(qhi[0][kc], bh, s[0][ni], 0, 0, 0);
                s[1][ni] = __builtin_amdgcn_mfma_f32_16x16x32_bf16(qhi[1][kc], bh, s[1][ni], 0, 0, 0);
                s[0][ni] = __builtin_amdgcn_mfma_f32_16x16x32_bf16(qlo[0][kc], bh, s[0][ni], 0, 0, 0);
                s[1][ni] = __builtin_amdgcn_mfma_f32_16x16x32_bf16(qlo[1][kc], bh, s[1][ni], 0, 0, 0);
                s[0][ni] = __builtin_amdgcn_mfma_f32_16x16x32_bf16(qhi[0][kc], bl, s[0][ni], 0, 0, 0);
                s[1][ni] = __builtin_amdgcn_mfma_f32_16x16x32_bf16(qhi[1][kc], bl, s[1][ni], 0, 0, 0);
            }
        }
#pragma unroll
        for (int mi = 0; mi < 2; ++mi)
#pragma unroll
            for (int ni = 0; ni < 2; ++ni)
#pragma unroll
                for (int r2 = 0; r2 < 4; ++r2)
                    sred[w][mi * 16 + quad * 4 + r2][ni * 16 + l16] = s[mi][ni][r2];
        __syncthreads();

        // --- parallel online softmax: thread (r = tid&31, g = tid>>5) ------
        const int r = tid & 31, g = tid >> 5;
        float sv[4];
#pragma unroll
        for (int j = 0; j < 4; ++j) {
            const int c = g * 4 + j;
            float x = sred[0][r][c] + sred[1][r][c] + sred[2][r][c] + sred[3][r][c];
            sv[j] = (kt0 + c < klen) ? x : -3.0e38f;
        }
        float pm = fmaxf(fmaxf(sv[0], sv[1]), fmaxf(sv[2], sv[3]));
        rowred[r][g] = pm;
        __syncthreads();
        float tm = rowred[r][0];
#pragma unroll
        for (int i = 1; i < 8; ++i) tm = fmaxf(tm, rowred[r][i]);
        const float mo    = mrow[r];
        const float mn    = fmaxf(mo, tm);
        const float alpha = __expf(mo - mn);
        float p[4], ps = 0.0f;
#pragma unroll
        for (int j = 0; j < 4; ++j) { p[j] = __expf(sv[j] - mn); ps += p[j]; }
        __syncthreads();
        rowred[r][g] = ps;
        us4 pw;
#pragma unroll
        for (int j = 0; j < 4; ++j) pw[j] = f2bf(p[j]);
        *(us4*)&pbuf[r][g * 4] = pw;
        __syncthreads();
        if (g == 0) {
            float ls = 0.0f;
#pragma unroll
            for (int i = 0; i < 8; ++i) ls += rowred[r][i];
            lrow[r] = lrow[r] * alpha + ls;
            mrow[r] = mn;
            arow[r] = alpha;
        }
        __syncthreads();

        // --- rescale O by alpha --------------------------------------------
        f32x4 av[2];
#pragma unroll
        for (int mi = 0; mi < 2; ++mi) av[mi] = *(const f32x4*)&arow[mi * 16 + quad * 4];
#pragma unroll
        for (int mi = 0; mi < 2; ++mi)
#pragma unroll
            for (int nd = 0; nd < 16; ++nd) o[mi][nd] *= av[mi];

        // --- PV: P A-frags from LDS, V B-frags 16B-contiguous from Vt ------
        s16x8 pa[2];
#pragma unroll
        for (int mi = 0; mi < 2; ++mi) {
            const u16* pp = &pbuf[mi * 16 + l16][quad * 8];
            us4 x0 = *(const us4*)pp;
            us4 x1 = *(const us4*)(pp + 4);
            s16x8 a;
#pragma unroll
            for (int j = 0; j < 4; ++j) { a[j] = (short)x0[j]; a[4 + j] = (short)x1[j]; }
            pa[mi] = a;
        }
#pragma unroll
        for (int nd = 0; nd < 16; ++nd) {
            const u16* vp = Vt + ((size_t)(b * DIM + w * 256 + nd * 16 + l16)) * KTOT
                               + kt0 + quad * 8;
            s16x8 vb = *(const s16x8*)vp;
            o[0][nd] = __builtin_amdgcn_mfma_f32_16x16x32_bf16(pa[0], vb, o[0][nd], 0, 0, 0);
            o[1][nd] = __builtin_amdgcn_mfma_f32_16x16x32_bf16(pa[1], vb, o[1][nd], 0, 0, 0);
        }
        __syncthreads();                       // pbuf/sred reused next tile
    }

    // --- epilogue: divide by l, store rows < qlen ---------------------------
    f32x4 li[2];
#pragma unroll
    for (int mi = 0; mi < 2; ++mi) {
        f32x4 lv = *(const f32x4*)&lrow[mi * 16 + quad * 4];
#pragma unroll
        for (int r2 = 0; r2 < 4; ++r2) li[mi][r2] = 1.0f / lv[r2];
    }
#pragma unroll
    for (int mi = 0; mi < 2; ++mi)
#pragma unroll
        for (int r2 = 0; r2 < 4; ++r2) {
            const int row = qt + mi * 16 + quad * 4 + r2;
            if (row < qlen) {
#pragma unroll
                for (int nd = 0; nd < 16; ++nd)
                    out[((size_t)(b * QT + row)) * DIM + w * 256 + nd * 16 + l16] =
                        o[mi][nd][r2] * li[mi][r2];
            }
        }
}

// ---------------------------------------------------------------------------
// Fallback (used only if ws_size is too small): fp32 vector flash,
// 8 waves/block, one q-row per wave, K/V rows staged once per block in LDS.
__global__ __launch_bounds__(512) void attn_naive(
    const float* __restrict__ Q, const float* __restrict__ K, const float* __restrict__ V,
    const int* __restrict__ Qlen, const int* __restrict__ Klen, float* __restrict__ out) {
    const int blk  = blockIdx.x;
    const int b    = blk >> 8;
    const int qb   = (blk & 255) << 3;
    const int qlen = Qlen[b];
    if (qb >= qlen) return;
    const int klen = Klen[b];
    const int tid  = threadIdx.x;
    const int wid  = tid >> 6, ln = tid & 63;
    const int q    = qb + wid;

    __shared__ float kbuf[1024], vbuf[1024];

    f32x4 qr[4];
#pragma unroll
    for (int i = 0; i < 4; ++i)
        qr[i] = *(const f32x4*)(Q + ((size_t)(b * QT + q)) * DIM + i * 256 + ln * 4);

    const f32x4 fzero = {0.0f, 0.0f, 0.0f, 0.0f};
    f32x4 acc[4] = {fzero, fzero, fzero, fzero};
    float m = -3.0e38f, l = 0.0f;

    for (int kt = 0; kt < klen; ++kt) {
        __syncthreads();
        if (tid < 256)
            *(f32x4*)&kbuf[tid * 4] = *(const f32x4*)(K + ((size_t)(b * KTOT + kt)) * DIM + tid * 4);
        else
            *(f32x4*)&vbuf[(tid - 256) * 4] =
                *(const f32x4*)(V + ((size_t)(b * KTOT + kt)) * DIM + (tid - 256) * 4);
        __syncthreads();
        float sp = 0.0f;
#pragma unroll
        for (int i = 0; i < 4; ++i) {
            f32x4 kv = *(const f32x4*)&kbuf[i * 256 + ln * 4];
            sp += qr[i][0] * kv[0] + qr[i][1] * kv[1] + qr[i][2] * kv[2] + qr[i][3] * kv[3];
        }
#pragma unroll
        for (int off = 1; off < 64; off <<= 1) sp += __shfl_xor(sp, off, 64);
        const float mn = fmaxf(m, sp);
        const float a  = __expf(m - mn);
        const float p  = __expf(sp - mn);
        l = l * a + p; m = mn;
#pragma unroll
        for (int i = 0; i < 4; ++i) {
            f32x4 vv = *(const f32x4*)&vbuf[i * 256 + ln * 4];
            acc[i] = acc[i] * a + vv * p;
        }
    }
    if (q < qlen) {
        const float inv = 1.0f / l;
#pragma unroll
        for (int i = 0; i < 4; ++i)
            *(f32x4*)(out + ((size_t)(b * QT + q)) * DIM + i * 256 + ln * 4) = acc[i] * inv;
    }
}

// ---------------------------------------------------------------------------
extern "C" void kernel_launch(void* const* d_in, const int* in_sizes, int n_in,
                              void* d_out, int out_size, void* d_ws, size_t ws_size,
                              hipStream_t stream) {
    (void)in_sizes; (void)n_in; (void)out_size;
    const float* Q    = (const float*)d_in[0];
    const float* K    = (const float*)d_in[1];
    const float* V    = (const float*)d_in[2];
    const int*   Qlen = (const int*)d_in[3];
    const int*   Klen = (const int*)d_in[4];
    float*       out  = (float*)d_out;

    fill_mean<<<dim3(BATCH * 16), dim3(256), 0, stream>>>(V, Qlen, out);

    const size_t HALF = (size_t)BATCH * KTOT * DIM;   // 33,554,432 elements
    if (ws_size >= HALF * 6) {                        // 201,326,592 bytes needed
        u16* khi = (u16*)d_ws;
        u16* klo = khi + HALF;
        u16* vt  = klo + HALF;
        conv_k<<<dim3(16384), dim3(256), 0, stream>>>(K, khi, klo);
        trans_v<<<dim3(8192), dim3(256), 0, stream>>>(V, vt);
        attn_main<<<dim3(1024), dim3(256), 0, stream>>>(Q, Qlen, Klen, khi, klo, vt, out);
    } else {
        attn_naive<<<dim3(4096), dim3(512), 0, stream>>>(Q, K, V, Qlen, Klen, out);
    }
}

// Round 2
// 786.650 us; speedup vs baseline: 2.3455x; 2.3455x over previous
//
#include <hip/hip_runtime.h>

#define BATCH 16
#define QT    2048
#define KTOT  2048
#define DIM   1024
#define NITEMS (BATCH * (QT / 32))   // 1024 work items (b, 32-row q-block)

typedef __attribute__((ext_vector_type(8))) _Float16 f16x8;
typedef __attribute__((ext_vector_type(4))) _Float16 f16x4;
typedef __attribute__((ext_vector_type(2))) _Float16 f16x2;
typedef __attribute__((ext_vector_type(4))) float    f32x4;

// ---------------------------------------------------------------------------
// K fp32 -> fp16 (single, no split: fp16 mantissa makes 2-term QK sufficient)
__global__ __launch_bounds__(256) void conv_k(const float* __restrict__ K,
                                              _Float16* __restrict__ Kf) {
    const size_t idx = ((size_t)blockIdx.x * 256 + threadIdx.x) * 8;
    f32x4 a0 = *(const f32x4*)(K + idx);
    f32x4 a1 = *(const f32x4*)(K + idx + 4);
    f16x8 h;
#pragma unroll
    for (int j = 0; j < 4; ++j) { h[j] = (_Float16)a0[j]; h[4 + j] = (_Float16)a1[j]; }
    *(f16x8*)(Kf + idx) = h;
}

// ---------------------------------------------------------------------------
// V[b][kt][d] fp32 -> Vt[b][d][kt] fp16 (PV B-frags become 16B-contiguous)
__global__ __launch_bounds__(256) void trans_v(const float* __restrict__ V,
                                               _Float16* __restrict__ Vt) {
    const int blk = blockIdx.x;
    const int b   = blk >> 9;
    const int kt0 = ((blk >> 4) & 31) << 6;
    const int d0  = (blk & 15) << 6;
    __shared__ _Float16 tbuf[64][65];
    const int tid = threadIdx.x;
    const int cr  = tid >> 4;
    const int c4  = (tid & 15) << 2;
#pragma unroll
    for (int p = 0; p < 4; ++p) {
        const int r = cr + p * 16;
        f32x4 v = *(const f32x4*)(V + ((size_t)(b * KTOT + kt0 + r)) * DIM + d0 + c4);
#pragma unroll
        for (int j = 0; j < 4; ++j) tbuf[r][c4 + j] = (_Float16)v[j];
    }
    __syncthreads();
#pragma unroll
    for (int p = 0; p < 4; ++p) {
        const int dr = cr + p * 16;
        f16x4 o;
#pragma unroll
        for (int j = 0; j < 4; ++j) o[j] = tbuf[c4 + j][dr];
        *(f16x4*)(Vt + ((size_t)(b * DIM + d0 + dr)) * KTOT + kt0 + c4) = o;
    }
}

// ---------------------------------------------------------------------------
// Rows q >= Q_len: reference softmax is exactly uniform over ALL KTOT keys ->
// output = column mean of V. Reads Vt (fp16, contiguous per (b,d) row).
__global__ __launch_bounds__(64) void fill_mean_vt(const _Float16* __restrict__ Vt,
                                                   const int* __restrict__ Qlen,
                                                   float* __restrict__ out) {
    const int row = blockIdx.x * 64 + threadIdx.x;      // 0 .. BATCH*DIM-1
    const int b = row >> 10, d = row & 1023;
    const f16x8* src = (const f16x8*)(Vt + (size_t)row * KTOT);
    float s = 0.0f;
    for (int i = 0; i < KTOT / 8; ++i) {
        f16x8 v = src[i];
#pragma unroll
        for (int j = 0; j < 8; ++j) s += (float)v[j];
    }
    const float mv = s * (1.0f / (float)KTOT);
    const int qlen = Qlen[b];
    for (int q = qlen; q < QT; ++q)
        out[((size_t)(b * QT + q)) * DIM + d] = mv;
}

// ---------------------------------------------------------------------------
// Main flash kernel. 512 thr = 8 waves; wave w owns D-slice [128w,128w+128).
// 32 q-rows per item; persistent blocks pull items from an atomic queue.
// QK^T = Qhi*K + Qlo*K (fp16 split Q, plain fp16 K).
__global__ __launch_bounds__(512, 2) void attn_main(
    const float* __restrict__ Q, const int* __restrict__ Qlen, const int* __restrict__ Klen,
    const _Float16* __restrict__ Kf, const _Float16* __restrict__ Vt,
    float* __restrict__ out, unsigned* __restrict__ counter) {

    __shared__ float    sred[8][32][33];
    __shared__ _Float16 pbuf[32][40];     // row stride 80B -> 16B-aligned frag reads
    __shared__ float    arow[32];
    __shared__ float    lrow[32];
    __shared__ unsigned item_s;

    const int tid  = threadIdx.x;
    const int w    = tid >> 6;            // wave 0..7
    const int ln   = tid & 63;
    const int l16  = ln & 15;
    const int quad = ln >> 4;
    const int d0   = w << 7;              // this wave's D-slice base
    // softmax mapping: row sr (0..31) owned by 16 consecutive tids (same wave)
    const int sr  = tid >> 4;
    const int scg = tid & 15;

    for (;;) {
        __syncthreads();                  // protect item_s + LDS reuse across items
        if (tid == 0) item_s = atomicAdd(counter, 1u);
        __syncthreads();
        const unsigned item = item_s;
        if (item >= NITEMS) break;
        const int b    = item >> 6;
        const int qt   = (item & 63) << 5;
        const int qlen = Qlen[b];
        if (qt >= qlen) continue;         // fill_mean_vt covers these rows
        const int klen = Klen[b];
        const int nkt  = (klen + 31) >> 5;

        // --- Q fragments (A-layout), fp16 hi/lo split, resident ------------
        f16x8 qh[2][4], ql[2][4];
#pragma unroll
        for (int mi = 0; mi < 2; ++mi)
#pragma unroll
            for (int kc = 0; kc < 4; ++kc) {
                const float* src = Q + ((size_t)(b * QT + qt + mi * 16 + l16)) * DIM
                                     + d0 + kc * 32 + quad * 8;
                f32x4 a0 = *(const f32x4*)src;
                f32x4 a1 = *(const f32x4*)(src + 4);
                f16x8 h, l;
#pragma unroll
                for (int j = 0; j < 4; ++j) {
                    _Float16 h0 = (_Float16)a0[j];
                    h[j] = h0; l[j] = (_Float16)(a0[j] - (float)h0);
                    _Float16 h1 = (_Float16)a1[j];
                    h[4 + j] = h1; l[4 + j] = (_Float16)(a1[j] - (float)h1);
                }
                qh[mi][kc] = h; ql[mi][kc] = l;
            }

        f32x4 o[2][8];
        const f32x4 fzero = {0.0f, 0.0f, 0.0f, 0.0f};
#pragma unroll
        for (int mi = 0; mi < 2; ++mi)
#pragma unroll
            for (int nd = 0; nd < 8; ++nd) o[mi][nd] = fzero;

        float msx = -3.0e38f, lsx = 0.0f;   // per-row softmax state (softmax mapping)

        // --- K preload for tile 0 ------------------------------------------
        f16x8 kf[2][4];
        {
            const _Float16* kb = Kf + ((size_t)(b * KTOT + l16)) * DIM + d0 + quad * 8;
#pragma unroll
            for (int ni = 0; ni < 2; ++ni)
#pragma unroll
                for (int kc = 0; kc < 4; ++kc)
                    kf[ni][kc] = *(const f16x8*)(kb + (size_t)(ni * 16) * DIM + kc * 32);
        }

        for (int t = 0; t < nkt; ++t) {
            const int kt0 = t << 5;
            // V prefetch (consumed after softmax, ~2 barriers later)
            f16x8 vf[8];
#pragma unroll
            for (int nd = 0; nd < 8; ++nd)
                vf[nd] = *(const f16x8*)(Vt + ((size_t)(b * DIM + d0 + nd * 16 + l16)) * KTOT
                                         + kt0 + quad * 8);
            // --- QK^T partial over this wave's slice (2-term fp16) ---------
            f32x4 s[2][2];
            s[0][0] = fzero; s[0][1] = fzero; s[1][0] = fzero; s[1][1] = fzero;
#pragma unroll
            for (int kc = 0; kc < 4; ++kc)
#pragma unroll
                for (int ni = 0; ni < 2; ++ni) {
                    s[0][ni] = __builtin_amdgcn_mfma_f32_16x16x32_f16(qh[0][kc], kf[ni][kc], s[0][ni], 0, 0, 0);
                    s[1][ni] = __builtin_amdgcn_mfma_f32_16x16x32_f16(qh[1][kc], kf[ni][kc], s[1][ni], 0, 0, 0);
                    s[0][ni] = __builtin_amdgcn_mfma_f32_16x16x32_f16(ql[0][kc], kf[ni][kc], s[0][ni], 0, 0, 0);
                    s[1][ni] = __builtin_amdgcn_mfma_f32_16x16x32_f16(ql[1][kc], kf[ni][kc], s[1][ni], 0, 0, 0);
                }
#pragma unroll
            for (int mi = 0; mi < 2; ++mi)
#pragma unroll
                for (int ni = 0; ni < 2; ++ni)
#pragma unroll
                    for (int r2 = 0; r2 < 4; ++r2)
                        sred[w][mi * 16 + quad * 4 + r2][ni * 16 + l16] = s[mi][ni][r2];
            __syncthreads();

            // --- softmax: thread (sr, scg) owns cols 2*scg, 2*scg+1 --------
            const int c0 = scg * 2, c1 = c0 + 1;
            float x0 = 0.0f, x1 = 0.0f;
#pragma unroll
            for (int ww = 0; ww < 8; ++ww) { x0 += sred[ww][sr][c0]; x1 += sred[ww][sr][c1]; }
            if (kt0 + c0 >= klen) x0 = -3.0e38f;
            if (kt0 + c1 >= klen) x1 = -3.0e38f;
            float pm = fmaxf(x0, x1);
#pragma unroll
            for (int off = 1; off < 16; off <<= 1) pm = fmaxf(pm, __shfl_xor(pm, off, 64));
            const float mn    = fmaxf(msx, pm);
            const float alpha = __expf(msx - mn);
            const float p0 = __expf(x0 - mn), p1 = __expf(x1 - mn);
            float ps = p0 + p1;
#pragma unroll
            for (int off = 1; off < 16; off <<= 1) ps += __shfl_xor(ps, off, 64);
            lsx = lsx * alpha + ps;
            msx = mn;
            f16x2 pw; pw[0] = (_Float16)p0; pw[1] = (_Float16)p1;
            *(f16x2*)&pbuf[sr][c0] = pw;
            if (scg == 0) arow[sr] = alpha;
            __syncthreads();

            // --- K prefetch for next tile (overlaps PV + next barrier) -----
            if (t + 1 < nkt) {
                const _Float16* kb = Kf + ((size_t)(b * KTOT + kt0 + 32 + l16)) * DIM
                                        + d0 + quad * 8;
#pragma unroll
                for (int ni = 0; ni < 2; ++ni)
#pragma unroll
                    for (int kc = 0; kc < 4; ++kc)
                        kf[ni][kc] = *(const f16x8*)(kb + (size_t)(ni * 16) * DIM + kc * 32);
            }

            // --- rescale O, then PV ----------------------------------------
            f32x4 av0 = *(const f32x4*)&arow[quad * 4];
            f32x4 av1 = *(const f32x4*)&arow[16 + quad * 4];
#pragma unroll
            for (int nd = 0; nd < 8; ++nd) { o[0][nd] *= av0; o[1][nd] *= av1; }

            f16x8 pa[2];
#pragma unroll
            for (int mi = 0; mi < 2; ++mi)
                pa[mi] = *(const f16x8*)&pbuf[mi * 16 + l16][quad * 8];
#pragma unroll
            for (int nd = 0; nd < 8; ++nd) {
                o[0][nd] = __builtin_amdgcn_mfma_f32_16x16x32_f16(pa[0], vf[nd], o[0][nd], 0, 0, 0);
                o[1][nd] = __builtin_amdgcn_mfma_f32_16x16x32_f16(pa[1], vf[nd], o[1][nd], 0, 0, 0);
            }
            // no trailing barrier: sred WAR protected by softmax barrier,
            // pbuf/arow WAR protected by next tile's post-sred barrier
        }

        // --- epilogue -------------------------------------------------------
        if (scg == 0) lrow[sr] = lsx;
        __syncthreads();
        f32x4 li0, li1;
#pragma unroll
        for (int r2 = 0; r2 < 4; ++r2) {
            li0[r2] = 1.0f / lrow[quad * 4 + r2];
            li1[r2] = 1.0f / lrow[16 + quad * 4 + r2];
        }
#pragma unroll
        for (int mi = 0; mi < 2; ++mi)
#pragma unroll
            for (int r2 = 0; r2 < 4; ++r2) {
                const int row = qt + mi * 16 + quad * 4 + r2;
                if (row < qlen) {
                    const float inv = mi ? li1[r2] : li0[r2];
#pragma unroll
                    for (int nd = 0; nd < 8; ++nd)
                        out[((size_t)(b * QT + row)) * DIM + d0 + nd * 16 + l16] =
                            o[mi][nd][r2] * inv;
                }
            }
    }
}

// ---------------------------------------------------------------------------
// Fallback path (only if ws too small — round-1 evidence says it isn't)
__global__ __launch_bounds__(256) void fill_mean_f32(const float* __restrict__ V,
                                                     const int* __restrict__ Qlen,
                                                     float* __restrict__ out) {
    const int b  = blockIdx.x >> 4;
    const int d0 = (blockIdx.x & 15) << 6;
    const int qlen = Qlen[b];
    const int tid = threadIdx.x;
    const int dc = d0 + (tid & 63);
    const int part = tid >> 6;
    __shared__ float red[4][64];
    __shared__ float mcol[64];
    float sm = 0.0f;
    for (int kt = part; kt < KTOT; kt += 4)
        sm += V[((size_t)(b * KTOT + kt)) * DIM + dc];
    red[part][tid & 63] = sm;
    __syncthreads();
    if (tid < 64)
        mcol[tid] = (red[0][tid] + red[1][tid] + red[2][tid] + red[3][tid]) * (1.0f / (float)KTOT);
    __syncthreads();
    const float mv = mcol[tid & 63];
    for (int q = qlen + part; q < QT; q += 4)
        out[((size_t)(b * QT + q)) * DIM + dc] = mv;
}

__global__ __launch_bounds__(512) void attn_naive(
    const float* __restrict__ Q, const float* __restrict__ K, const float* __restrict__ V,
    const int* __restrict__ Qlen, const int* __restrict__ Klen, float* __restrict__ out) {
    const int blk  = blockIdx.x;
    const int b    = blk >> 8;
    const int qb   = (blk & 255) << 3;
    const int qlen = Qlen[b];
    if (qb >= qlen) return;
    const int klen = Klen[b];
    const int tid  = threadIdx.x;
    const int wid  = tid >> 6, ln = tid & 63;
    const int q    = qb + wid;
    __shared__ float kbuf[1024], vbuf[1024];
    f32x4 qr[4];
#pragma unroll
    for (int i = 0; i < 4; ++i)
        qr[i] = *(const f32x4*)(Q + ((size_t)(b * QT + q)) * DIM + i * 256 + ln * 4);
    const f32x4 fzero = {0.0f, 0.0f, 0.0f, 0.0f};
    f32x4 acc[4] = {fzero, fzero, fzero, fzero};
    float m = -3.0e38f, l = 0.0f;
    for (int kt = 0; kt < klen; ++kt) {
        __syncthreads();
        if (tid < 256)
            *(f32x4*)&kbuf[tid * 4] = *(const f32x4*)(K + ((size_t)(b * KTOT + kt)) * DIM + tid * 4);
        else
            *(f32x4*)&vbuf[(tid - 256) * 4] =
                *(const f32x4*)(V + ((size_t)(b * KTOT + kt)) * DIM + (tid - 256) * 4);
        __syncthreads();
        float sp = 0.0f;
#pragma unroll
        for (int i = 0; i < 4; ++i) {
            f32x4 kv = *(const f32x4*)&kbuf[i * 256 + ln * 4];
            sp += qr[i][0] * kv[0] + qr[i][1] * kv[1] + qr[i][2] * kv[2] + qr[i][3] * kv[3];
        }
#pragma unroll
        for (int off = 1; off < 64; off <<= 1) sp += __shfl_xor(sp, off, 64);
        const float mn = fmaxf(m, sp);
        const float a  = __expf(m - mn);
        const float p  = __expf(sp - mn);
        l = l * a + p; m = mn;
#pragma unroll
        for (int i = 0; i < 4; ++i) {
            f32x4 vv = *(const f32x4*)&vbuf[i * 256 + ln * 4];
            acc[i] = acc[i] * a + vv * p;
        }
    }
    if (q < qlen) {
        const float inv = 1.0f / l;
#pragma unroll
        for (int i = 0; i < 4; ++i)
            *(f32x4*)(out + ((size_t)(b * QT + q)) * DIM + i * 256 + ln * 4) = acc[i] * inv;
    }
}

// ---------------------------------------------------------------------------
extern "C" void kernel_launch(void* const* d_in, const int* in_sizes, int n_in,
                              void* d_out, int out_size, void* d_ws, size_t ws_size,
                              hipStream_t stream) {
    (void)in_sizes; (void)n_in; (void)out_size;
    const float* Q    = (const float*)d_in[0];
    const float* K    = (const float*)d_in[1];
    const float* V    = (const float*)d_in[2];
    const int*   Qlen = (const int*)d_in[3];
    const int*   Klen = (const int*)d_in[4];
    float*       out  = (float*)d_out;

    const size_t HALF = (size_t)BATCH * KTOT * DIM;          // 33,554,432 elements
    const size_t NEED = HALF * 2 /*Kf*/ * sizeof(_Float16) + 64; // ~128 MB + counter
    if (ws_size >= NEED) {
        _Float16* kf = (_Float16*)d_ws;
        _Float16* vt = kf + HALF;
        unsigned* ctr = (unsigned*)((char*)d_ws + HALF * 2 * sizeof(_Float16));
        hipMemsetAsync(ctr, 0, sizeof(unsigned), stream);
        conv_k<<<dim3(16384), dim3(256), 0, stream>>>(K, kf);
        trans_v<<<dim3(8192), dim3(256), 0, stream>>>(V, vt);
        fill_mean_vt<<<dim3((BATCH * DIM) / 64), dim3(64), 0, stream>>>(vt, Qlen, out);
        attn_main<<<dim3(512), dim3(512), 0, stream>>>(Q, Qlen, Klen, kf, vt, out, ctr);
    } else {
        fill_mean_f32<<<dim3(BATCH * 16), dim3(256), 0, stream>>>(V, Qlen, out);
        attn_naive<<<dim3(4096), dim3(512), 0, stream>>>(Q, K, V, Qlen, Klen, out);
    }
}